// Round 5
// baseline (185.106 us; speedup 1.0000x reference)
//
#include <hip/hip_runtime.h>

#define B_ 8
#define T_ 16
#define D_ 1536
#define N_ 12
#define KH_ 2
#define G_ 6
#define H_ 128
#define S_ 8192
#define NCHUNK 32
#define SPLITS 8

typedef __attribute__((ext_vector_type(8))) short bf16x8;
typedef __attribute__((ext_vector_type(4))) float f32x4;
typedef __attribute__((ext_vector_type(4))) unsigned short u16x4;

__device__ __forceinline__ unsigned short f2bf(float x) {
    unsigned u = __float_as_uint(x);
    u += 0x7fffu + ((u >> 16) & 1u);
    return (unsigned short)(u >> 16);
}
__device__ __forceinline__ float bf2f(unsigned short h) {
    return __uint_as_float(((unsigned)h) << 16);
}

// ---------------------------------------------------------------------------
// Split-K MFMA GEMM with split-bf16 (3-product) accuracy. (unchanged)
// ---------------------------------------------------------------------------
__global__ __launch_bounds__(256, 4) void gemm_splitk(
    const float* __restrict__ A,
    const float* __restrict__ W0, int n0, int ldb0,
    const float* __restrict__ W1, int n1, int ldb1,
    const float* __restrict__ W2, int ldb2,
    float* __restrict__ part, int NTOT, int Kdim)
{
    __shared__ __align__(16) unsigned short Ah[64][40], Al[64][40];
    __shared__ __align__(16) unsigned short Bh[64][40], Bl[64][40];
    const int tid = threadIdx.x;
    const int wave = tid >> 6, lane = tid & 63;
    const int col = lane & 15, g = lane >> 4;
    const int row0 = blockIdx.y * 64;
    const int c0 = blockIdx.x * 64;
    const int ks = Kdim / gridDim.z;
    const int k0 = blockIdx.z * ks;

    const float* Bp; int ldb, bc0;
    if (c0 < n0)           { Bp = W0; ldb = ldb0; bc0 = c0; }
    else if (c0 < n0 + n1) { Bp = W1; ldb = ldb1; bc0 = c0 - n0; }
    else                   { Bp = W2; ldb = ldb2; bc0 = c0 - n0 - n1; }

    f32x4 acc[4];
#pragma unroll
    for (int nt = 0; nt < 4; ++nt) acc[nt] = (f32x4){0.f, 0.f, 0.f, 0.f};

    for (int kk = 0; kk < ks; kk += 32) {
        __syncthreads();
        if (tid < 128) {
#pragma unroll
            for (int c = tid; c < 512; c += 128) {
                int r = c >> 3, k4 = c & 7;
                float4 v = *(const float4*)&A[(size_t)(row0 + r) * Kdim + k0 + kk + k4 * 4];
                float f[4] = {v.x, v.y, v.z, v.w};
                u16x4 hv, lv;
#pragma unroll
                for (int i = 0; i < 4; ++i) {
                    unsigned short hh = f2bf(f[i]);
                    hv[i] = hh; lv[i] = f2bf(f[i] - bf2f(hh));
                }
                *(u16x4*)&Ah[r][k4 * 4] = hv;
                *(u16x4*)&Al[r][k4 * 4] = lv;
            }
        } else {
            int t2 = tid - 128;
            int kq = t2 >> 4, cq = t2 & 15;
            float a[4][4];
#pragma unroll
            for (int r = 0; r < 4; ++r) {
                float4 v = *(const float4*)&Bp[(size_t)(k0 + kk + kq * 4 + r) * ldb + bc0 + cq * 4];
                a[r][0] = v.x; a[r][1] = v.y; a[r][2] = v.z; a[r][3] = v.w;
            }
#pragma unroll
            for (int cc = 0; cc < 4; ++cc) {
                u16x4 hv, lv;
#pragma unroll
                for (int r = 0; r < 4; ++r) {
                    unsigned short hh = f2bf(a[r][cc]);
                    hv[r] = hh; lv[r] = f2bf(a[r][cc] - bf2f(hh));
                }
                *(u16x4*)&Bh[cq * 4 + cc][kq * 4] = hv;
                *(u16x4*)&Bl[cq * 4 + cc][kq * 4] = lv;
            }
        }
        __syncthreads();

        bf16x8 ah = *(const bf16x8*)&Ah[wave * 16 + col][g * 8];
        bf16x8 al = *(const bf16x8*)&Al[wave * 16 + col][g * 8];
#pragma unroll
        for (int nt = 0; nt < 4; ++nt) {
            bf16x8 bh = *(const bf16x8*)&Bh[nt * 16 + col][g * 8];
            bf16x8 bl = *(const bf16x8*)&Bl[nt * 16 + col][g * 8];
            acc[nt] = __builtin_amdgcn_mfma_f32_16x16x32_bf16(ah, bh, acc[nt], 0, 0, 0);
            acc[nt] = __builtin_amdgcn_mfma_f32_16x16x32_bf16(ah, bl, acc[nt], 0, 0, 0);
            acc[nt] = __builtin_amdgcn_mfma_f32_16x16x32_bf16(al, bh, acc[nt], 0, 0, 0);
        }
    }
#pragma unroll
    for (int nt = 0; nt < 4; ++nt)
#pragma unroll
        for (int j = 0; j < 4; ++j) {
            size_t prow = (size_t)blockIdx.z * 128 + row0 + wave * 16 + g * 4 + j;
            part[prow * NTOT + c0 + nt * 16 + col] = acc[nt][j];
        }
}

// ---------------------------------------------------------------------------
// Reduce SPLITS partials + bias + RoPE. (unchanged)
// ---------------------------------------------------------------------------
__global__ __launch_bounds__(256) void rope_reduce(
    const float* __restrict__ part,
    const float* __restrict__ bq, const float* __restrict__ bk,
    const float* __restrict__ bv,
    const int* __restrict__ seg, const int* __restrict__ curp,
    float* __restrict__ q_rope, float* __restrict__ k_new,
    float* __restrict__ v_new)
{
    const int row = blockIdx.x;
    const int b = row >> 4, t = row & 15;
    const int tid = threadIdx.x;
    __shared__ float S[2048];
    __shared__ float sc[64][2];

    const int CUR = curp[0];
    int c = 0;
    for (int tt = 0; tt <= t; ++tt) c += (seg[b * T_ + tt] != 0) ? 1 : 0;
    int pos = max(c - 1, 0) + CUR;

    if (tid < 64) {
        float frac = (2.0f * tid) / (float)H_;
        float ts = expf(frac * logf(1000000.0f));
        float ang = (float)pos / ts;
        sc[tid][0] = sinf(ang);
        sc[tid][1] = cosf(ang);
    }
    for (int e = tid; e < 2048; e += 256) {
        float s = 0.f;
#pragma unroll
        for (int sp = 0; sp < SPLITS; ++sp)
            s += part[((size_t)sp * 128 + row) * 2048 + e];
        S[e] = s;
    }
    __syncthreads();

    for (int e = tid; e < 768; e += 256) {
        int n = e >> 6, i = e & 63;
        float x1 = S[n * 128 + i] + bq[n * 128 + i];
        float x2 = S[n * 128 + i + 64] + bq[n * 128 + i + 64];
        float s = sc[i][0], co = sc[i][1];
        q_rope[(size_t)row * 1536 + n * 128 + i]      = x1 * co - x2 * s;
        q_rope[(size_t)row * 1536 + n * 128 + i + 64] = x2 * co + x1 * s;
    }
    if (tid < 128) {
        int n = tid >> 6, i = tid & 63;
        float x1 = S[1536 + n * 128 + i] + bk[n * 128 + i];
        float x2 = S[1536 + n * 128 + i + 64] + bk[n * 128 + i + 64];
        float s = sc[i][0], co = sc[i][1];
        k_new[(size_t)row * 256 + n * 128 + i]      = x1 * co - x2 * s;
        k_new[(size_t)row * 256 + n * 128 + i + 64] = x2 * co + x1 * s;
    }
    v_new[(size_t)row * 256 + tid] = S[1792 + tid] + bv[tid];
}

// ---------------------------------------------------------------------------
// MFMA flash attention. NCHUNK=32 -> 512 blocks = 2 blocks/CU (12 waves/CU).
// K split-bf16 (accuracy-critical QK); V and P single-bf16.
// 2-deep register-staged prefetch retained.
// ---------------------------------------------------------------------------
__global__ __launch_bounds__(384, 3) void attn_mfma(
    const float* __restrict__ q_rope, const float* __restrict__ k_new,
    const float* __restrict__ v_new,
    const float* __restrict__ k_cache, const float* __restrict__ v_cache,
    const int* __restrict__ seg, const int* __restrict__ start_ind,
    const int* __restrict__ curp,
    float* __restrict__ part)
{
    const int chunk = blockIdx.x, b = blockIdx.y, kh = blockIdx.z;
    const int tid = threadIdx.x;
    const int wave = tid >> 6, lane = tid & 63;
    const int col = lane & 15, g = lane >> 4;
    const float scale = 0.088388347648318447f;
    const float NEG_INF = -__builtin_inff();

    const int CUR = curp[0];
    const int SPAN = CUR + T_;
    const int CH = (SPAN + NCHUNK - 1) / NCHUNK;
    const int s0 = chunk * CH;
    const int s1 = min(s0 + CH, SPAN);

    int st = start_ind[b];
    if (st < 0) {
        st = 0;
        for (int tt = 0; tt < T_; ++tt)
            if (seg[b * T_ + tt] != 0) { st = tt; break; }
    }

    __shared__ __align__(16) unsigned short K_hi[32][136], K_lo[32][136]; // 17.0 KiB
    __shared__ __align__(16) unsigned short Vt_hi[128][40];               // 10.0 KiB
    __shared__ __align__(16) unsigned short P_hi[6][16][40];              //  7.5 KiB

    // ---- Q prologue ----
    const int qbase = wave * 16;
    const int qi_a = qbase + col;
    const int t_a = (qi_a * 171) >> 10;
    const int gh_a = qi_a - t_a * G_;
    const float* qp = &q_rope[(((size_t)b * T_ + t_a) * N_ + kh * G_ + gh_a) * H_];
    bf16x8 qh[4], ql[4];
#pragma unroll
    for (int ks = 0; ks < 4; ++ks) {
        float4 va = *(const float4*)&qp[ks * 32 + g * 8];
        float4 vb = *(const float4*)&qp[ks * 32 + g * 8 + 4];
        float f[8] = {va.x, va.y, va.z, va.w, vb.x, vb.y, vb.z, vb.w};
#pragma unroll
        for (int i = 0; i < 8; ++i) {
            float xs = f[i] * scale;
            unsigned short hh = f2bf(xs);
            qh[ks][i] = (short)hh;
            ql[ks][i] = (short)f2bf(xs - bf2f(hh));
        }
    }

    int qpos_r[4], segid_r[4];
#pragma unroll
    for (int j = 0; j < 4; ++j) {
        int qi_c = qbase + g * 4 + j;
        int t_c = (qi_c * 171) >> 10;
        segid_r[j] = seg[b * T_ + t_c];
        qpos_r[j] = CUR + t_c - st;
    }

    float m[4], lsum[4];
#pragma unroll
    for (int j = 0; j < 4; ++j) { m[j] = NEG_INF; lsum[j] = 0.f; }
    f32x4 oacc[8];
#pragma unroll
    for (int nt = 0; nt < 8; ++nt) oacc[nt] = (f32x4){0.f, 0.f, 0.f, 0.f};

    const int vky4 = tid >> 5, vd4 = tid & 31;

    auto issueK = [&](float4* kreg, int stile) {
#pragma unroll
        for (int i = 0; i < 3; ++i) {
            int c = tid + i * 384;
            float4 v = {0.f, 0.f, 0.f, 0.f};
            if (c < 1024) {
                int key = c >> 5, d4 = c & 31;
                int s = stile + key;
                if (s < s1) {
                    const float* src = (s < CUR)
                        ? &k_cache[((((size_t)b * S_ + s) * KH_) + kh) * H_ + d4 * 4]
                        : &k_new[((((size_t)b * T_ + (s - CUR)) * KH_) + kh) * H_ + d4 * 4];
                    v = *(const float4*)src;
                }
            }
            kreg[i] = v;
        }
    };
    auto issueV = [&](float4* vreg, int stile) {
        if (tid < 256) {
#pragma unroll
            for (int r = 0; r < 4; ++r) {
                int s = stile + vky4 * 4 + r;
                float4 v = {0.f, 0.f, 0.f, 0.f};
                if (s < s1) {
                    const float* src = (s < CUR)
                        ? &v_cache[((((size_t)b * S_ + s) * KH_) + kh) * H_ + vd4 * 4]
                        : &v_new[((((size_t)b * T_ + (s - CUR)) * KH_) + kh) * H_ + vd4 * 4];
                    v = *(const float4*)src;
                }
                vreg[r] = v;
            }
        }
    };
    auto convertKV = [&](const float4* kreg, const float4* vreg) {
#pragma unroll
        for (int i = 0; i < 3; ++i) {
            int c = tid + i * 384;
            if (c < 1024) {
                int key = c >> 5, d4 = c & 31;
                float f[4] = {kreg[i].x, kreg[i].y, kreg[i].z, kreg[i].w};
                u16x4 hv, lv;
#pragma unroll
                for (int q = 0; q < 4; ++q) {
                    unsigned short hh = f2bf(f[q]);
                    hv[q] = hh; lv[q] = f2bf(f[q] - bf2f(hh));
                }
                *(u16x4*)&K_hi[key][d4 * 4] = hv;
                *(u16x4*)&K_lo[key][d4 * 4] = lv;
            }
        }
        if (tid < 256) {
            float a[4][4];
#pragma unroll
            for (int r = 0; r < 4; ++r) {
                a[r][0] = vreg[r].x; a[r][1] = vreg[r].y;
                a[r][2] = vreg[r].z; a[r][3] = vreg[r].w;
            }
#pragma unroll
            for (int dd = 0; dd < 4; ++dd) {
                u16x4 hv;
#pragma unroll
                for (int r = 0; r < 4; ++r) hv[r] = f2bf(a[r][dd]);
                *(u16x4*)&Vt_hi[vd4 * 4 + dd][vky4 * 4] = hv;
            }
        }
    };

    auto computeTile = [&](int stile) {
        const bool full = (s1 - stile) > 16;
        f32x4 sacc0 = {0.f, 0.f, 0.f, 0.f}, sacc1 = {0.f, 0.f, 0.f, 0.f};
#pragma unroll
        for (int ks = 0; ks < 4; ++ks) {
            bf16x8 k0h = *(const bf16x8*)&K_hi[col][ks * 32 + g * 8];
            bf16x8 k0l = *(const bf16x8*)&K_lo[col][ks * 32 + g * 8];
            sacc0 = __builtin_amdgcn_mfma_f32_16x16x32_bf16(qh[ks], k0h, sacc0, 0, 0, 0);
            sacc0 = __builtin_amdgcn_mfma_f32_16x16x32_bf16(qh[ks], k0l, sacc0, 0, 0, 0);
            sacc0 = __builtin_amdgcn_mfma_f32_16x16x32_bf16(ql[ks], k0h, sacc0, 0, 0, 0);
        }
        if (full) {
#pragma unroll
            for (int ks = 0; ks < 4; ++ks) {
                bf16x8 k1h = *(const bf16x8*)&K_hi[16 + col][ks * 32 + g * 8];
                bf16x8 k1l = *(const bf16x8*)&K_lo[16 + col][ks * 32 + g * 8];
                sacc1 = __builtin_amdgcn_mfma_f32_16x16x32_bf16(qh[ks], k1h, sacc1, 0, 0, 0);
                sacc1 = __builtin_amdgcn_mfma_f32_16x16x32_bf16(qh[ks], k1l, sacc1, 0, 0, 0);
                sacc1 = __builtin_amdgcn_mfma_f32_16x16x32_bf16(ql[ks], k1h, sacc1, 0, 0, 0);
            }
        }

        float rj[4];
        const int skey0 = stile + col, skey1 = stile + 16 + col;
#pragma unroll
        for (int j = 0; j < 4; ++j) {
            bool v0 = (skey0 < s1) && (skey0 - st <= qpos_r[j]) &&
                      (((skey0 >= st) ? 1 : 0) == segid_r[j]);
            bool v1 = (skey1 < s1) && (skey1 - st <= qpos_r[j]) &&
                      (((skey1 >= st) ? 1 : 0) == segid_r[j]);
            float lg0 = v0 ? sacc0[j] : NEG_INF;
            float lg1 = v1 ? sacc1[j] : NEG_INF;
            float tm = fmaxf(lg0, lg1);
            tm = fmaxf(tm, __shfl_xor(tm, 1));
            tm = fmaxf(tm, __shfl_xor(tm, 2));
            tm = fmaxf(tm, __shfl_xor(tm, 4));
            tm = fmaxf(tm, __shfl_xor(tm, 8));
            float mn = fmaxf(m[j], tm);
            float r, p0, p1;
            if (mn == NEG_INF) { r = 1.f; p0 = 0.f; p1 = 0.f; }
            else {
                r  = __expf(m[j] - mn);
                p0 = __expf(lg0 - mn);
                p1 = __expf(lg1 - mn);
            }
            float ps = p0 + p1;
            ps += __shfl_xor(ps, 1);
            ps += __shfl_xor(ps, 2);
            ps += __shfl_xor(ps, 4);
            ps += __shfl_xor(ps, 8);
            lsum[j] = lsum[j] * r + ps;
            m[j] = mn;
            rj[j] = r;
            int row = g * 4 + j;
            P_hi[wave][row][col]      = f2bf(p0);
            P_hi[wave][row][16 + col] = f2bf(p1);
        }

#pragma unroll
        for (int nt = 0; nt < 8; ++nt) {
#pragma unroll
            for (int j = 0; j < 4; ++j) oacc[nt][j] *= rj[j];
        }

        bf16x8 pah = *(const bf16x8*)&P_hi[wave][col][g * 8];
#pragma unroll
        for (int nt = 0; nt < 8; ++nt) {
            bf16x8 vbh = *(const bf16x8*)&Vt_hi[nt * 16 + col][g * 8];
            oacc[nt] = __builtin_amdgcn_mfma_f32_16x16x32_bf16(pah, vbh, oacc[nt], 0, 0, 0);
        }
    };

    const int ntiles = (s1 - s0 + 31) >> 5;
    float4 kregA[3], vregA[4], kregB[3], vregB[4];

    issueK(kregA, s0); issueV(vregA, s0);
    if (ntiles > 1) { issueK(kregB, s0 + 32); issueV(vregB, s0 + 32); }

    for (int ti = 0; ti < ntiles; ti += 2) {
        {
            convertKV(kregA, vregA);
            __syncthreads();
            if (ti + 2 < ntiles) {
                issueK(kregA, s0 + (ti + 2) * 32);
                issueV(vregA, s0 + (ti + 2) * 32);
            }
            computeTile(s0 + ti * 32);
            __syncthreads();
        }
        if (ti + 1 < ntiles) {
            convertKV(kregB, vregB);
            __syncthreads();
            if (ti + 3 < ntiles) {
                issueK(kregB, s0 + (ti + 3) * 32);
                issueV(vregB, s0 + (ti + 3) * 32);
            }
            computeTile(s0 + (ti + 1) * 32);
            __syncthreads();
        }
    }

    // ---- write partials ----
    const size_t base_q = (((size_t)chunk * B_ + b) * KH_ + kh) * 96;
#pragma unroll
    for (int j = 0; j < 4; ++j) {
        int qi = qbase + g * 4 + j;
        size_t pb = (base_q + qi) * 132;
        if (col == 0) { part[pb] = m[j]; part[pb + 1] = lsum[j]; }
#pragma unroll
        for (int nt = 0; nt < 8; ++nt)
            part[pb + 2 + nt * 16 + col] = oacc[nt][j];
    }
}

// ---------------------------------------------------------------------------
// Combine per-chunk partials -> qkv (b,t,N,H)
// ---------------------------------------------------------------------------
__global__ __launch_bounds__(256) void combine_kernel(
    const float* __restrict__ part, float* __restrict__ qkv)
{
    const int row = blockIdx.x;
    const int b = row >> 4, t = row & 15;
    const int tid = threadIdx.x;
    const int half = tid >> 7, h = tid & 127;
    const size_t cstride = (size_t)B_ * KH_ * 96 * 132;

    for (int nb = 0; nb < N_; nb += 2) {
        int n = nb + half;
        int kh = n / G_, g = n - kh * G_;
        int qi = t * G_ + g;
        size_t base0 = (((size_t)b * KH_ + kh) * 96 + qi) * 132;
        float M = -__builtin_inff();
        for (int c = 0; c < NCHUNK; ++c)
            M = fmaxf(M, part[base0 + c * cstride]);
        float den = 0.f, num = 0.f;
        for (int c = 0; c < NCHUNK; ++c) {
            float mc = part[base0 + c * cstride];
            float e = (M == -__builtin_inff() || mc == -__builtin_inff())
                          ? 0.f : expf(mc - M);
            den += e * part[base0 + c * cstride + 1];
            num += e * part[base0 + c * cstride + 2 + h];
        }
        qkv[(size_t)row * (N_ * H_) + n * H_ + h] = (den > 0.f) ? num / den : 0.f;
    }
}

// ---------------------------------------------------------------------------
__global__ __launch_bounds__(256) void sum_reduce(
    const float* __restrict__ part, float* __restrict__ out, int n)
{
    int i = blockIdx.x * 256 + threadIdx.x;
    if (i < n) {
        float s = 0.f;
#pragma unroll
        for (int sp = 0; sp < SPLITS; ++sp) s += part[(size_t)sp * n + i];
        out[i] = s;
    }
}

// ---------------------------------------------------------------------------
extern "C" void kernel_launch(void* const* d_in, const int* in_sizes, int n_in,
                              void* d_out, int out_size, void* d_ws, size_t ws_size,
                              hipStream_t stream)
{
    (void)in_sizes; (void)n_in; (void)out_size; (void)ws_size;
    const float* x       = (const float*)d_in[0];
    const float* k_cache = (const float*)d_in[1];
    const float* v_cache = (const float*)d_in[2];
    const float* wq      = (const float*)d_in[3];
    const float* bq      = (const float*)d_in[4];
    const float* wk      = (const float*)d_in[5];
    const float* bk      = (const float*)d_in[6];
    const float* wv      = (const float*)d_in[7];
    const float* bv      = (const float*)d_in[8];
    const float* wo      = (const float*)d_in[9];
    const int*   seg     = (const int*)d_in[10];
    const int*   start_i = (const int*)d_in[11];
    const int*   curp    = (const int*)d_in[12];
    float* out = (float*)d_out;
    float* ws  = (float*)d_ws;

    // aliased region: projection partials (SPLITS*128*2048 = 2,097,152 floats)
    // and attention partials (NCHUNK*B*KH*96*132 = 6,488,064 floats).
    // Lifetimes are disjoint (stream-ordered), so share one region.
    const size_t PSZ  = (size_t)NCHUNK * B_ * KH_ * 96 * 132; // 6,488,064
    const size_t QSZ  = (size_t)B_ * T_ * N_ * H_;            // 196,608
    const size_t KSZ  = (size_t)B_ * T_ * KH_ * H_;           // 32,768
    float* partP  = ws;           // projections (both) use this
    float* partA  = ws;           // attention partials alias it
    float* q_rope = ws + PSZ;
    float* k_new  = q_rope + QSZ;
    float* v_new  = k_new + KSZ;
    float* qkv    = v_new + KSZ;

    gemm_splitk<<<dim3(32, 2, SPLITS), 256, 0, stream>>>(
        x, wq, 1536, 1536, wk, 256, 256, wv, 256, partP, 2048, D_);

    rope_reduce<<<B_ * T_, 256, 0, stream>>>(partP, bq, bk, bv, seg, curp,
                                             q_rope, k_new, v_new);

    attn_mfma<<<dim3(NCHUNK, B_, KH_), 384, 0, stream>>>(
        q_rope, k_new, v_new, k_cache, v_cache, seg, start_i, curp, partA);

    combine_kernel<<<B_ * T_, 256, 0, stream>>>(partA, qkv);

    gemm_splitk<<<dim3(24, 2, SPLITS), 256, 0, stream>>>(
        qkv, wo, 1536, 1536, wo, 0, 1536, wo, 1536, partP, 1536, N_ * H_);

    sum_reduce<<<(B_ * T_ * D_ + 255) / 256, 256, 0, stream>>>(
        partP, out, B_ * T_ * D_);
}

// Round 6
// 98.802 us; speedup vs baseline: 1.8735x; 1.8735x over previous
//
#include <hip/hip_runtime.h>
#include <hip/hip_bf16.h>

#define B_ 8
#define T_ 16
#define D_ 1536
#define N_ 12
#define KH_ 2
#define G_ 6
#define H_ 128
#define S_ 8192
#define NCHUNK 16
#define SPLITS 8

typedef __attribute__((ext_vector_type(8))) short bf16x8;
typedef __attribute__((ext_vector_type(4))) float f32x4;
typedef __attribute__((ext_vector_type(4))) unsigned short u16x4;

__device__ __forceinline__ unsigned short f2bf(float x) {
    unsigned u = __float_as_uint(x);
    u += 0x7fffu + ((u >> 16) & 1u);
    return (unsigned short)(u >> 16);
}
__device__ __forceinline__ float bf2f(unsigned short h) {
    return __uint_as_float(((unsigned)h) << 16);
}

// ---------------------------------------------------------------------------
// Split-K MFMA GEMM with split-bf16 (3-product) accuracy. (unchanged)
// ---------------------------------------------------------------------------
__global__ __launch_bounds__(256, 4) void gemm_splitk(
    const float* __restrict__ A,
    const float* __restrict__ W0, int n0, int ldb0,
    const float* __restrict__ W1, int n1, int ldb1,
    const float* __restrict__ W2, int ldb2,
    float* __restrict__ part, int NTOT, int Kdim)
{
    __shared__ __align__(16) unsigned short Ah[64][40], Al[64][40];
    __shared__ __align__(16) unsigned short Bh[64][40], Bl[64][40];
    const int tid = threadIdx.x;
    const int wave = tid >> 6, lane = tid & 63;
    const int col = lane & 15, g = lane >> 4;
    const int row0 = blockIdx.y * 64;
    const int c0 = blockIdx.x * 64;
    const int ks = Kdim / gridDim.z;
    const int k0 = blockIdx.z * ks;

    const float* Bp; int ldb, bc0;
    if (c0 < n0)           { Bp = W0; ldb = ldb0; bc0 = c0; }
    else if (c0 < n0 + n1) { Bp = W1; ldb = ldb1; bc0 = c0 - n0; }
    else                   { Bp = W2; ldb = ldb2; bc0 = c0 - n0 - n1; }

    f32x4 acc[4];
#pragma unroll
    for (int nt = 0; nt < 4; ++nt) acc[nt] = (f32x4){0.f, 0.f, 0.f, 0.f};

    for (int kk = 0; kk < ks; kk += 32) {
        __syncthreads();
        if (tid < 128) {
#pragma unroll
            for (int c = tid; c < 512; c += 128) {
                int r = c >> 3, k4 = c & 7;
                float4 v = *(const float4*)&A[(size_t)(row0 + r) * Kdim + k0 + kk + k4 * 4];
                float f[4] = {v.x, v.y, v.z, v.w};
                u16x4 hv, lv;
#pragma unroll
                for (int i = 0; i < 4; ++i) {
                    unsigned short hh = f2bf(f[i]);
                    hv[i] = hh; lv[i] = f2bf(f[i] - bf2f(hh));
                }
                *(u16x4*)&Ah[r][k4 * 4] = hv;
                *(u16x4*)&Al[r][k4 * 4] = lv;
            }
        } else {
            int t2 = tid - 128;
            int kq = t2 >> 4, cq = t2 & 15;
            float a[4][4];
#pragma unroll
            for (int r = 0; r < 4; ++r) {
                float4 v = *(const float4*)&Bp[(size_t)(k0 + kk + kq * 4 + r) * ldb + bc0 + cq * 4];
                a[r][0] = v.x; a[r][1] = v.y; a[r][2] = v.z; a[r][3] = v.w;
            }
#pragma unroll
            for (int cc = 0; cc < 4; ++cc) {
                u16x4 hv, lv;
#pragma unroll
                for (int r = 0; r < 4; ++r) {
                    unsigned short hh = f2bf(a[r][cc]);
                    hv[r] = hh; lv[r] = f2bf(a[r][cc] - bf2f(hh));
                }
                *(u16x4*)&Bh[cq * 4 + cc][kq * 4] = hv;
                *(u16x4*)&Bl[cq * 4 + cc][kq * 4] = lv;
            }
        }
        __syncthreads();

        bf16x8 ah = *(const bf16x8*)&Ah[wave * 16 + col][g * 8];
        bf16x8 al = *(const bf16x8*)&Al[wave * 16 + col][g * 8];
#pragma unroll
        for (int nt = 0; nt < 4; ++nt) {
            bf16x8 bh = *(const bf16x8*)&Bh[nt * 16 + col][g * 8];
            bf16x8 bl = *(const bf16x8*)&Bl[nt * 16 + col][g * 8];
            acc[nt] = __builtin_amdgcn_mfma_f32_16x16x32_bf16(ah, bh, acc[nt], 0, 0, 0);
            acc[nt] = __builtin_amdgcn_mfma_f32_16x16x32_bf16(ah, bl, acc[nt], 0, 0, 0);
            acc[nt] = __builtin_amdgcn_mfma_f32_16x16x32_bf16(al, bh, acc[nt], 0, 0, 0);
        }
    }
#pragma unroll
    for (int nt = 0; nt < 4; ++nt)
#pragma unroll
        for (int j = 0; j < 4; ++j) {
            size_t prow = (size_t)blockIdx.z * 128 + row0 + wave * 16 + g * 4 + j;
            part[prow * NTOT + c0 + nt * 16 + col] = acc[nt][j];
        }
}

// ---------------------------------------------------------------------------
// Reduce SPLITS partials + bias + RoPE. (unchanged)
// ---------------------------------------------------------------------------
__global__ __launch_bounds__(256) void rope_reduce(
    const float* __restrict__ part,
    const float* __restrict__ bq, const float* __restrict__ bk,
    const float* __restrict__ bv,
    const int* __restrict__ seg, const int* __restrict__ curp,
    float* __restrict__ q_rope, float* __restrict__ k_new,
    float* __restrict__ v_new)
{
    const int row = blockIdx.x;
    const int b = row >> 4, t = row & 15;
    const int tid = threadIdx.x;
    __shared__ float S[2048];
    __shared__ float sc[64][2];

    const int CUR = curp[0];
    int c = 0;
    for (int tt = 0; tt <= t; ++tt) c += (seg[b * T_ + tt] != 0) ? 1 : 0;
    int pos = max(c - 1, 0) + CUR;

    if (tid < 64) {
        float frac = (2.0f * tid) / (float)H_;
        float ts = expf(frac * logf(1000000.0f));
        float ang = (float)pos / ts;
        sc[tid][0] = sinf(ang);
        sc[tid][1] = cosf(ang);
    }
    for (int e = tid; e < 2048; e += 256) {
        float s = 0.f;
#pragma unroll
        for (int sp = 0; sp < SPLITS; ++sp)
            s += part[((size_t)sp * 128 + row) * 2048 + e];
        S[e] = s;
    }
    __syncthreads();

    for (int e = tid; e < 768; e += 256) {
        int n = e >> 6, i = e & 63;
        float x1 = S[n * 128 + i] + bq[n * 128 + i];
        float x2 = S[n * 128 + i + 64] + bq[n * 128 + i + 64];
        float s = sc[i][0], co = sc[i][1];
        q_rope[(size_t)row * 1536 + n * 128 + i]      = x1 * co - x2 * s;
        q_rope[(size_t)row * 1536 + n * 128 + i + 64] = x2 * co + x1 * s;
    }
    if (tid < 128) {
        int n = tid >> 6, i = tid & 63;
        float x1 = S[1536 + n * 128 + i] + bk[n * 128 + i];
        float x2 = S[1536 + n * 128 + i + 64] + bk[n * 128 + i + 64];
        float s = sc[i][0], co = sc[i][1];
        k_new[(size_t)row * 256 + n * 128 + i]      = x1 * co - x2 * s;
        k_new[(size_t)row * 256 + n * 128 + i + 64] = x2 * co + x1 * s;
    }
    v_new[(size_t)row * 256 + tid] = S[1792 + tid] + bv[tid];
}

// ---------------------------------------------------------------------------
// Barrier-free MFMA flash attention.
// grid = (NCHUNK=16, B, KH) = 256 blocks (1/CU), 384 thr = 6 independent waves.
// Each wave: 16 queries, streams its chunk's K/V with NO __syncthreads.
// K: global -> regs (frag layout) -> hi/lo bf16 in-register (packed cvt).
// V: global -> regs -> single bf16 -> wave-PRIVATE LDS transpose (bit-swizzled
//    row ((dim&7)<<4)|(dim>>3) puts both write & read at the b128 bank floor).
// P: wave-private LDS slice for C-layout -> A-frag relayout.
// ---------------------------------------------------------------------------
__global__ __launch_bounds__(384) void attn_mfma(
    const float* __restrict__ q_rope, const float* __restrict__ k_new,
    const float* __restrict__ v_new,
    const float* __restrict__ k_cache, const float* __restrict__ v_cache,
    const int* __restrict__ seg, const int* __restrict__ start_ind,
    const int* __restrict__ curp,
    float* __restrict__ part)
{
    const int chunk = blockIdx.x, b = blockIdx.y, kh = blockIdx.z;
    const int tid = threadIdx.x;
    const int wave = tid >> 6, lane = tid & 63;
    const int col = lane & 15, g = lane >> 4;
    const float scale = 0.088388347648318447f;
    const float NEG_INF = -__builtin_inff();

    const int CUR = curp[0];
    const int SPAN = CUR + T_;
    const int CH = (SPAN + NCHUNK - 1) / NCHUNK;
    const int s0 = chunk * CH;
    const int s1 = min(s0 + CH, SPAN);

    int st = start_ind[b];
    if (st < 0) {
        st = 0;
        for (int tt = 0; tt < T_; ++tt)
            if (seg[b * T_ + tt] != 0) { st = tt; break; }
    }

    __shared__ __align__(16) unsigned short Vt[6][128][32]; // 48 KiB, per-wave slices
    __shared__ __align__(16) unsigned short Pl[6][16][40];  // 7.5 KiB, per-wave slices

    // ---- Q prologue: A-frags in registers, hi/lo, scale folded ----
    const int qbase = wave * 16;
    const int qi_a = qbase + col;
    const int t_a = (qi_a * 171) >> 10;
    const int gh_a = qi_a - t_a * G_;
    const float* qp = &q_rope[(((size_t)b * T_ + t_a) * N_ + kh * G_ + gh_a) * H_];
    bf16x8 qh[4], ql[4];
#pragma unroll
    for (int ks = 0; ks < 4; ++ks) {
        float4 va = *(const float4*)&qp[ks * 32 + g * 8];
        float4 vb = *(const float4*)&qp[ks * 32 + g * 8 + 4];
        float f[8] = {va.x, va.y, va.z, va.w, vb.x, vb.y, vb.z, vb.w};
#pragma unroll
        for (int i = 0; i < 8; ++i) {
            float xs = f[i] * scale;
            unsigned short hh = f2bf(xs);
            qh[ks][i] = (short)hh;
            ql[ks][i] = (short)f2bf(xs - bf2f(hh));
        }
    }

    int qpos_r[4], segid_r[4];
#pragma unroll
    for (int j = 0; j < 4; ++j) {
        int qi_c = qbase + g * 4 + j;
        int t_c = (qi_c * 171) >> 10;
        segid_r[j] = seg[b * T_ + t_c];
        qpos_r[j] = CUR + t_c - st;
    }

    float m[4], lsum[4];
#pragma unroll
    for (int j = 0; j < 4; ++j) { m[j] = NEG_INF; lsum[j] = 0.f; }
    f32x4 oacc[8];
#pragma unroll
    for (int nt = 0; nt < 8; ++nt) oacc[nt] = (f32x4){0.f, 0.f, 0.f, 0.f};

    auto krow = [&](int s) -> const float* {
        s = min(s, SPAN - 1);
        return (s < CUR)
            ? &k_cache[((((size_t)b * S_ + s) * KH_) + kh) * H_]
            : &k_new[((((size_t)b * T_ + (s - CUR)) * KH_) + kh) * H_];
    };
    auto vrow = [&](int s) -> const float* {
        s = min(s, SPAN - 1);
        return (s < CUR)
            ? &v_cache[((((size_t)b * S_ + s) * KH_) + kh) * H_]
            : &v_new[((((size_t)b * T_ + (s - CUR)) * KH_) + kh) * H_];
    };

    // K frag loads: lane (col,g) loads keys stile+col, stile+16+col.
    auto loadK = [&](float4* kf, int stile) {
#pragma unroll
        for (int kt = 0; kt < 2; ++kt) {
            const float* kr = krow(stile + kt * 16 + col);
#pragma unroll
            for (int ks = 0; ks < 4; ++ks) {
                kf[kt * 8 + ks * 2 + 0] = *(const float4*)(kr + ks * 32 + g * 8);
                kf[kt * 8 + ks * 2 + 1] = *(const float4*)(kr + ks * 32 + g * 8 + 4);
            }
        }
    };
    // V loads: lane (col,g) loads keys stile+g*8+r at dims [col*8, col*8+8).
    auto loadV = [&](float4* vf, int stile) {
#pragma unroll
        for (int r = 0; r < 8; ++r) {
            const float* vr = vrow(stile + g * 8 + r);
            vf[r * 2 + 0] = *(const float4*)(vr + col * 8);
            vf[r * 2 + 1] = *(const float4*)(vr + col * 8 + 4);
        }
    };

    const int ntiles = (s1 - s0 + 31) >> 5;
    float4 kf[16], vf[16];
    loadK(kf, s0);

    for (int ti = 0; ti < ntiles; ++ti) {
        const int stile = s0 + ti * 32;
        loadV(vf, stile);   // in flight under QK + softmax

        // ---- QK^T: convert K frags hi/lo + MFMA (3-product) ----
        f32x4 sacc0 = {0.f, 0.f, 0.f, 0.f}, sacc1 = {0.f, 0.f, 0.f, 0.f};
#pragma unroll
        for (int kt = 0; kt < 2; ++kt) {
#pragma unroll
            for (int ks = 0; ks < 4; ++ks) {
                float4 a = kf[kt * 8 + ks * 2], bb = kf[kt * 8 + ks * 2 + 1];
                float f[8] = {a.x, a.y, a.z, a.w, bb.x, bb.y, bb.z, bb.w};
                union { bf16x8 v; __hip_bfloat162 h2[4]; } Hh, Ll;
#pragma unroll
                for (int i = 0; i < 4; ++i) {
                    float2 p = make_float2(f[2 * i], f[2 * i + 1]);
                    Hh.h2[i] = __float22bfloat162_rn(p);
                    float2 q = __bfloat1622float2(Hh.h2[i]);
                    Ll.h2[i] = __float22bfloat162_rn(make_float2(p.x - q.x, p.y - q.y));
                }
                if (kt == 0) {
                    sacc0 = __builtin_amdgcn_mfma_f32_16x16x32_bf16(qh[ks], Hh.v, sacc0, 0, 0, 0);
                    sacc0 = __builtin_amdgcn_mfma_f32_16x16x32_bf16(ql[ks], Hh.v, sacc0, 0, 0, 0);
                    sacc0 = __builtin_amdgcn_mfma_f32_16x16x32_bf16(qh[ks], Ll.v, sacc0, 0, 0, 0);
                } else {
                    sacc1 = __builtin_amdgcn_mfma_f32_16x16x32_bf16(qh[ks], Hh.v, sacc1, 0, 0, 0);
                    sacc1 = __builtin_amdgcn_mfma_f32_16x16x32_bf16(ql[ks], Hh.v, sacc1, 0, 0, 0);
                    sacc1 = __builtin_amdgcn_mfma_f32_16x16x32_bf16(qh[ks], Ll.v, sacc1, 0, 0, 0);
                }
            }
        }

        // prefetch next tile's K (covered by softmax + V-convert + PV)
        if (ti + 1 < ntiles) loadK(kf, stile + 32);

        // ---- mask + online softmax ----
        float rj[4];
        const int skey0 = stile + col, skey1 = stile + 16 + col;
#pragma unroll
        for (int j = 0; j < 4; ++j) {
            bool v0 = (skey0 < s1) && (skey0 - st <= qpos_r[j]) &&
                      (((skey0 >= st) ? 1 : 0) == segid_r[j]);
            bool v1 = (skey1 < s1) && (skey1 - st <= qpos_r[j]) &&
                      (((skey1 >= st) ? 1 : 0) == segid_r[j]);
            float lg0 = v0 ? sacc0[j] : NEG_INF;
            float lg1 = v1 ? sacc1[j] : NEG_INF;
            float tm = fmaxf(lg0, lg1);
            tm = fmaxf(tm, __shfl_xor(tm, 1));
            tm = fmaxf(tm, __shfl_xor(tm, 2));
            tm = fmaxf(tm, __shfl_xor(tm, 4));
            tm = fmaxf(tm, __shfl_xor(tm, 8));
            float mn = fmaxf(m[j], tm);
            float r, p0, p1;
            if (mn == NEG_INF) { r = 1.f; p0 = 0.f; p1 = 0.f; }
            else {
                r  = __expf(m[j] - mn);
                p0 = __expf(lg0 - mn);
                p1 = __expf(lg1 - mn);
            }
            float ps = p0 + p1;
            ps += __shfl_xor(ps, 1);
            ps += __shfl_xor(ps, 2);
            ps += __shfl_xor(ps, 4);
            ps += __shfl_xor(ps, 8);
            lsum[j] = lsum[j] * r + ps;
            m[j] = mn;
            rj[j] = r;
            int row = g * 4 + j;
            Pl[wave][row][col]      = f2bf(p0);
            Pl[wave][row][16 + col] = f2bf(p1);
        }

#pragma unroll
        for (int nt = 0; nt < 8; ++nt) {
#pragma unroll
            for (int j = 0; j < 4; ++j) oacc[nt][j] *= rj[j];
        }

        // ---- V: convert + transpose into wave-private LDS ----
#pragma unroll
        for (int c = 0; c < 8; ++c) {
            float fr[8];
#pragma unroll
            for (int r = 0; r < 8; ++r)
                fr[r] = ((const float*)&vf[r * 2 + (c >> 2)])[c & 3];
            union { bf16x8 v; __hip_bfloat162 h2[4]; } W;
#pragma unroll
            for (int i = 0; i < 4; ++i)
                W.h2[i] = __float22bfloat162_rn(make_float2(fr[2 * i], fr[2 * i + 1]));
            // dim = col*8 + c ; swizzled row = ((dim&7)<<4)|(dim>>3) = (c<<4)|col
            *(bf16x8*)&Vt[wave][(c << 4) | col][g * 8] = W.v;
        }

        // ---- PV ----
        bf16x8 pa = *(const bf16x8*)&Pl[wave][col][g * 8];
#pragma unroll
        for (int nt = 0; nt < 8; ++nt) {
            // dim = nt*16+col ; swizzled row = ((col&7)<<4) | (nt*2) | (col>>3)
            bf16x8 vb = *(const bf16x8*)&Vt[wave][((col & 7) << 4) | (nt * 2) | (col >> 3)][g * 8];
            oacc[nt] = __builtin_amdgcn_mfma_f32_16x16x32_bf16(pa, vb, oacc[nt], 0, 0, 0);
        }
    }

    // ---- write partials ----
    const size_t base_q = (((size_t)chunk * B_ + b) * KH_ + kh) * 96;
#pragma unroll
    for (int j = 0; j < 4; ++j) {
        int qi = qbase + g * 4 + j;
        size_t pb = (base_q + qi) * 132;
        if (col == 0) { part[pb] = m[j]; part[pb + 1] = lsum[j]; }
#pragma unroll
        for (int nt = 0; nt < 8; ++nt)
            part[pb + 2 + nt * 16 + col] = oacc[nt][j];
    }
}

// ---------------------------------------------------------------------------
// Combine per-chunk partials -> qkv (b,t,N,H)
// ---------------------------------------------------------------------------
__global__ __launch_bounds__(256) void combine_kernel(
    const float* __restrict__ part, float* __restrict__ qkv)
{
    const int row = blockIdx.x;
    const int b = row >> 4, t = row & 15;
    const int tid = threadIdx.x;
    const int half = tid >> 7, h = tid & 127;
    const size_t cstride = (size_t)B_ * KH_ * 96 * 132;

    for (int nb = 0; nb < N_; nb += 2) {
        int n = nb + half;
        int kh = n / G_, g = n - kh * G_;
        int qi = t * G_ + g;
        size_t base0 = (((size_t)b * KH_ + kh) * 96 + qi) * 132;
        float M = -__builtin_inff();
        for (int c = 0; c < NCHUNK; ++c)
            M = fmaxf(M, part[base0 + c * cstride]);
        float den = 0.f, num = 0.f;
        for (int c = 0; c < NCHUNK; ++c) {
            float mc = part[base0 + c * cstride];
            float e = (M == -__builtin_inff() || mc == -__builtin_inff())
                          ? 0.f : expf(mc - M);
            den += e * part[base0 + c * cstride + 1];
            num += e * part[base0 + c * cstride + 2 + h];
        }
        qkv[(size_t)row * (N_ * H_) + n * H_ + h] = (den > 0.f) ? num / den : 0.f;
    }
}

// ---------------------------------------------------------------------------
__global__ __launch_bounds__(256) void sum_reduce(
    const float* __restrict__ part, float* __restrict__ out, int n)
{
    int i = blockIdx.x * 256 + threadIdx.x;
    if (i < n) {
        float s = 0.f;
#pragma unroll
        for (int sp = 0; sp < SPLITS; ++sp) s += part[(size_t)sp * n + i];
        out[i] = s;
    }
}

// ---------------------------------------------------------------------------
extern "C" void kernel_launch(void* const* d_in, const int* in_sizes, int n_in,
                              void* d_out, int out_size, void* d_ws, size_t ws_size,
                              hipStream_t stream)
{
    (void)in_sizes; (void)n_in; (void)out_size; (void)ws_size;
    const float* x       = (const float*)d_in[0];
    const float* k_cache = (const float*)d_in[1];
    const float* v_cache = (const float*)d_in[2];
    const float* wq      = (const float*)d_in[3];
    const float* bq      = (const float*)d_in[4];
    const float* wk      = (const float*)d_in[5];
    const float* bk      = (const float*)d_in[6];
    const float* wv      = (const float*)d_in[7];
    const float* bv      = (const float*)d_in[8];
    const float* wo      = (const float*)d_in[9];
    const int*   seg     = (const int*)d_in[10];
    const int*   start_i = (const int*)d_in[11];
    const int*   curp    = (const int*)d_in[12];
    float* out = (float*)d_out;
    float* ws  = (float*)d_ws;

    // aliased region: projection partials (2,097,152 floats) and attention
    // partials (NCHUNK*B*KH*96*132 = 3,244,032 floats); lifetimes disjoint.
    const size_t PSZ  = (size_t)NCHUNK * B_ * KH_ * 96 * 132; // 3,244,032
    const size_t QSZ  = (size_t)B_ * T_ * N_ * H_;            // 196,608
    const size_t KSZ  = (size_t)B_ * T_ * KH_ * H_;           // 32,768
    float* partP  = ws;
    float* partA  = ws;
    float* q_rope = ws + PSZ;
    float* k_new  = q_rope + QSZ;
    float* v_new  = k_new + KSZ;
    float* qkv    = v_new + KSZ;

    gemm_splitk<<<dim3(32, 2, SPLITS), 256, 0, stream>>>(
        x, wq, 1536, 1536, wk, 256, 256, wv, 256, partP, 2048, D_);

    rope_reduce<<<B_ * T_, 256, 0, stream>>>(partP, bq, bk, bv, seg, curp,
                                             q_rope, k_new, v_new);

    attn_mfma<<<dim3(NCHUNK, B_, KH_), 384, 0, stream>>>(
        q_rope, k_new, v_new, k_cache, v_cache, seg, start_i, curp, partA);

    combine_kernel<<<B_ * T_, 256, 0, stream>>>(partA, qkv);

    gemm_splitk<<<dim3(24, 2, SPLITS), 256, 0, stream>>>(
        qkv, wo, 1536, 1536, wo, 0, 1536, wo, 1536, partP, 1536, N_ * H_);

    sum_reduce<<<(B_ * T_ * D_ + 255) / 256, 256, 0, stream>>>(
        partP, out, B_ * T_ * D_);
}

// Round 7
// 96.490 us; speedup vs baseline: 1.9184x; 1.0240x over previous
//
#include <hip/hip_runtime.h>
#include <hip/hip_bf16.h>

#define B_ 8
#define T_ 16
#define D_ 1536
#define N_ 12
#define KH_ 2
#define G_ 6
#define H_ 128
#define S_ 8192
#define NCHUNK 16
#define SPLITS 8

typedef __attribute__((ext_vector_type(8))) short bf16x8;
typedef __attribute__((ext_vector_type(4))) float f32x4;
typedef __attribute__((ext_vector_type(4))) unsigned short u16x4;

__device__ __forceinline__ unsigned short f2bf(float x) {
    unsigned u = __float_as_uint(x);
    u += 0x7fffu + ((u >> 16) & 1u);
    return (unsigned short)(u >> 16);
}
__device__ __forceinline__ float bf2f(unsigned short h) {
    return __uint_as_float(((unsigned)h) << 16);
}

// async global->LDS, 16B per lane. LDS dest is wave-uniform base + lane*16;
// per-lane swizzle must live in the GLOBAL source address (m173 / rule #21).
__device__ __forceinline__ void gload16(const float* g, void* l) {
    __builtin_amdgcn_global_load_lds(
        (const __attribute__((address_space(1))) unsigned int*)g,
        (__attribute__((address_space(3))) unsigned int*)l,
        16, 0, 0);
}

// ---------------------------------------------------------------------------
// Split-K MFMA GEMM with split-bf16 (3-product) accuracy. (unchanged)
// ---------------------------------------------------------------------------
__global__ __launch_bounds__(256, 4) void gemm_splitk(
    const float* __restrict__ A,
    const float* __restrict__ W0, int n0, int ldb0,
    const float* __restrict__ W1, int n1, int ldb1,
    const float* __restrict__ W2, int ldb2,
    float* __restrict__ part, int NTOT, int Kdim)
{
    __shared__ __align__(16) unsigned short Ah[64][40], Al[64][40];
    __shared__ __align__(16) unsigned short Bh[64][40], Bl[64][40];
    const int tid = threadIdx.x;
    const int wave = tid >> 6, lane = tid & 63;
    const int col = lane & 15, g = lane >> 4;
    const int row0 = blockIdx.y * 64;
    const int c0 = blockIdx.x * 64;
    const int ks = Kdim / gridDim.z;
    const int k0 = blockIdx.z * ks;

    const float* Bp; int ldb, bc0;
    if (c0 < n0)           { Bp = W0; ldb = ldb0; bc0 = c0; }
    else if (c0 < n0 + n1) { Bp = W1; ldb = ldb1; bc0 = c0 - n0; }
    else                   { Bp = W2; ldb = ldb2; bc0 = c0 - n0 - n1; }

    f32x4 acc[4];
#pragma unroll
    for (int nt = 0; nt < 4; ++nt) acc[nt] = (f32x4){0.f, 0.f, 0.f, 0.f};

    for (int kk = 0; kk < ks; kk += 32) {
        __syncthreads();
        if (tid < 128) {
#pragma unroll
            for (int c = tid; c < 512; c += 128) {
                int r = c >> 3, k4 = c & 7;
                float4 v = *(const float4*)&A[(size_t)(row0 + r) * Kdim + k0 + kk + k4 * 4];
                float f[4] = {v.x, v.y, v.z, v.w};
                u16x4 hv, lv;
#pragma unroll
                for (int i = 0; i < 4; ++i) {
                    unsigned short hh = f2bf(f[i]);
                    hv[i] = hh; lv[i] = f2bf(f[i] - bf2f(hh));
                }
                *(u16x4*)&Ah[r][k4 * 4] = hv;
                *(u16x4*)&Al[r][k4 * 4] = lv;
            }
        } else {
            int t2 = tid - 128;
            int kq = t2 >> 4, cq = t2 & 15;
            float a[4][4];
#pragma unroll
            for (int r = 0; r < 4; ++r) {
                float4 v = *(const float4*)&Bp[(size_t)(k0 + kk + kq * 4 + r) * ldb + bc0 + cq * 4];
                a[r][0] = v.x; a[r][1] = v.y; a[r][2] = v.z; a[r][3] = v.w;
            }
#pragma unroll
            for (int cc = 0; cc < 4; ++cc) {
                u16x4 hv, lv;
#pragma unroll
                for (int r = 0; r < 4; ++r) {
                    unsigned short hh = f2bf(a[r][cc]);
                    hv[r] = hh; lv[r] = f2bf(a[r][cc] - bf2f(hh));
                }
                *(u16x4*)&Bh[cq * 4 + cc][kq * 4] = hv;
                *(u16x4*)&Bl[cq * 4 + cc][kq * 4] = lv;
            }
        }
        __syncthreads();

        bf16x8 ah = *(const bf16x8*)&Ah[wave * 16 + col][g * 8];
        bf16x8 al = *(const bf16x8*)&Al[wave * 16 + col][g * 8];
#pragma unroll
        for (int nt = 0; nt < 4; ++nt) {
            bf16x8 bh = *(const bf16x8*)&Bh[nt * 16 + col][g * 8];
            bf16x8 bl = *(const bf16x8*)&Bl[nt * 16 + col][g * 8];
            acc[nt] = __builtin_amdgcn_mfma_f32_16x16x32_bf16(ah, bh, acc[nt], 0, 0, 0);
            acc[nt] = __builtin_amdgcn_mfma_f32_16x16x32_bf16(ah, bl, acc[nt], 0, 0, 0);
            acc[nt] = __builtin_amdgcn_mfma_f32_16x16x32_bf16(al, bh, acc[nt], 0, 0, 0);
        }
    }
#pragma unroll
    for (int nt = 0; nt < 4; ++nt)
#pragma unroll
        for (int j = 0; j < 4; ++j) {
            size_t prow = (size_t)blockIdx.z * 128 + row0 + wave * 16 + g * 4 + j;
            part[prow * NTOT + c0 + nt * 16 + col] = acc[nt][j];
        }
}

// ---------------------------------------------------------------------------
// Reduce SPLITS partials + bias + RoPE. (unchanged)
// ---------------------------------------------------------------------------
__global__ __launch_bounds__(256) void rope_reduce(
    const float* __restrict__ part,
    const float* __restrict__ bq, const float* __restrict__ bk,
    const float* __restrict__ bv,
    const int* __restrict__ seg, const int* __restrict__ curp,
    float* __restrict__ q_rope, float* __restrict__ k_new,
    float* __restrict__ v_new)
{
    const int row = blockIdx.x;
    const int b = row >> 4, t = row & 15;
    const int tid = threadIdx.x;
    __shared__ float S[2048];
    __shared__ float sc[64][2];

    const int CUR = curp[0];
    int c = 0;
    for (int tt = 0; tt <= t; ++tt) c += (seg[b * T_ + tt] != 0) ? 1 : 0;
    int pos = max(c - 1, 0) + CUR;

    if (tid < 64) {
        float frac = (2.0f * tid) / (float)H_;
        float ts = expf(frac * logf(1000000.0f));
        float ang = (float)pos / ts;
        sc[tid][0] = sinf(ang);
        sc[tid][1] = cosf(ang);
    }
    for (int e = tid; e < 2048; e += 256) {
        float s = 0.f;
#pragma unroll
        for (int sp = 0; sp < SPLITS; ++sp)
            s += part[((size_t)sp * 128 + row) * 2048 + e];
        S[e] = s;
    }
    __syncthreads();

    for (int e = tid; e < 768; e += 256) {
        int n = e >> 6, i = e & 63;
        float x1 = S[n * 128 + i] + bq[n * 128 + i];
        float x2 = S[n * 128 + i + 64] + bq[n * 128 + i + 64];
        float s = sc[i][0], co = sc[i][1];
        q_rope[(size_t)row * 1536 + n * 128 + i]      = x1 * co - x2 * s;
        q_rope[(size_t)row * 1536 + n * 128 + i + 64] = x2 * co + x1 * s;
    }
    if (tid < 128) {
        int n = tid >> 6, i = tid & 63;
        float x1 = S[1536 + n * 128 + i] + bk[n * 128 + i];
        float x2 = S[1536 + n * 128 + i + 64] + bk[n * 128 + i + 64];
        float s = sc[i][0], co = sc[i][1];
        k_new[(size_t)row * 256 + n * 128 + i]      = x1 * co - x2 * s;
        k_new[(size_t)row * 256 + n * 128 + i + 64] = x2 * co + x1 * s;
    }
    v_new[(size_t)row * 256 + tid] = S[1792 + tid] + bv[tid];
}

// ---------------------------------------------------------------------------
// MFMA flash attention, 2-phase async-staged (T3-min + T14 + m173 swizzle).
// grid = (NCHUNK=16, B, KH) = 256 blocks, 384 thr = 6 waves (16 queries each).
// K: global_load_lds -> LDS f32, XOR-swizzled via per-lane SOURCE address;
//    read back with the same XOR -> bank-floor ds_read_b128.
// V: global->reg (issued before compute) -> bf16 -> transposed LDS after.
// Both double-buffered; stage for tile t+1 issued BEFORE computing tile t,
// so the __syncthreads vmcnt-drain lands after a full compute phase of cover.
// All-bf16 QK/PV (single product); split-bf16 kept only in the GEMMs.
// ---------------------------------------------------------------------------
__global__ __launch_bounds__(384, 3) void attn_mfma(
    const float* __restrict__ q_rope, const float* __restrict__ k_new,
    const float* __restrict__ v_new,
    const float* __restrict__ k_cache, const float* __restrict__ v_cache,
    const int* __restrict__ seg, const int* __restrict__ start_ind,
    const int* __restrict__ curp,
    float* __restrict__ part)
{
    const int chunk = blockIdx.x, b = blockIdx.y, kh = blockIdx.z;
    const int tid = threadIdx.x;
    const int wave = tid >> 6, lane = tid & 63;
    const int col = lane & 15, g = lane >> 4;
    const float scale = 0.088388347648318447f;
    const float NEG_INF = -__builtin_inff();

    const int CUR = curp[0];
    const int SPAN = CUR + T_;
    const int CH = (SPAN + NCHUNK - 1) / NCHUNK;
    const int s0 = chunk * CH;
    const int s1 = min(s0 + CH, SPAN);

    int st = start_ind[b];
    if (st < 0) {
        st = 0;
        for (int tt = 0; tt < T_; ++tt)
            if (seg[b * T_ + tt] != 0) { st = tt; break; }
    }

    __shared__ __align__(16) float Ksw[2][32][128];           // 32 KiB (dbuf)
    __shared__ __align__(16) unsigned short Vt[2][128][40];   // 20 KiB (dbuf)
    __shared__ __align__(16) unsigned short Pl[6][16][40];    // 7.5 KiB

    // ---- Q prologue: single-bf16 A-frags, scale folded ----
    const int qbase = wave * 16;
    const int qi_a = qbase + col;
    const int t_a = (qi_a * 171) >> 10;
    const int gh_a = qi_a - t_a * G_;
    const float* qp = &q_rope[(((size_t)b * T_ + t_a) * N_ + kh * G_ + gh_a) * H_];
    bf16x8 qf[4];
#pragma unroll
    for (int ks = 0; ks < 4; ++ks) {
        float4 va = *(const float4*)&qp[ks * 32 + g * 8];
        float4 vb = *(const float4*)&qp[ks * 32 + g * 8 + 4];
        float f[8] = {va.x, va.y, va.z, va.w, vb.x, vb.y, vb.z, vb.w};
        union { bf16x8 v; __hip_bfloat162 h2[4]; } W;
#pragma unroll
        for (int i = 0; i < 4; ++i)
            W.h2[i] = __float22bfloat162_rn(make_float2(f[2 * i] * scale, f[2 * i + 1] * scale));
        qf[ks] = W.v;
    }

    int qpos_r[4], segid_r[4];
#pragma unroll
    for (int j = 0; j < 4; ++j) {
        int qi_c = qbase + g * 4 + j;
        int t_c = (qi_c * 171) >> 10;
        segid_r[j] = seg[b * T_ + t_c];
        qpos_r[j] = CUR + t_c - st;
    }

    float m[4], lsum[4];
#pragma unroll
    for (int j = 0; j < 4; ++j) { m[j] = NEG_INF; lsum[j] = 0.f; }
    f32x4 oacc[8];
#pragma unroll
    for (int nt = 0; nt < 8; ++nt) oacc[nt] = (f32x4){0.f, 0.f, 0.f, 0.f};

    auto krow = [&](int s) -> const float* {
        s = min(s, SPAN - 1);
        return (s < CUR)
            ? &k_cache[((((size_t)b * S_ + s) * KH_) + kh) * H_]
            : &k_new[((((size_t)b * T_ + (s - CUR)) * KH_) + kh) * H_];
    };
    auto vrow = [&](int s) -> const float* {
        s = min(s, SPAN - 1);
        return (s < CUR)
            ? &v_cache[((((size_t)b * S_ + s) * KH_) + kh) * H_]
            : &v_new[((((size_t)b * T_ + (s - CUR)) * KH_) + kh) * H_];
    };

    // ---- K stage: 1024 16B-slots; slot idx -> (row, s); source pre-swizzled
    auto stageK = [&](int bufi, int stile) {
#pragma unroll
        for (int i = 0; i < 3; ++i) {
            int idx = tid + i * 384;
            if (idx < 1024) {                      // wave-uniform guard
                int row = idx >> 5, s = idx & 31;
                int sg = s ^ (row & 7);            // swizzle in SOURCE addr
                gload16(krow(stile + row) + sg * 4, &Ksw[bufi][row][s * 4]);
            }
        }
    };
    // ---- V loads into regs (issued early; tid<256: 4 keys x 4 dims) ----
    const int vky4 = tid >> 5, vd4 = tid & 31;
    auto loadV = [&](float4* vreg, int stile) {
        if (tid < 256) {
#pragma unroll
            for (int r = 0; r < 4; ++r)
                vreg[r] = *(const float4*)(vrow(stile + vky4 * 4 + r) + vd4 * 4);
        }
    };
    // ---- V convert + transposed write (after compute, before barrier) ----
    auto writeV = [&](int bufi, const float4* vreg) {
        if (tid < 256) {
            float a[4][4];
#pragma unroll
            for (int r = 0; r < 4; ++r) {
                a[r][0] = vreg[r].x; a[r][1] = vreg[r].y;
                a[r][2] = vreg[r].z; a[r][3] = vreg[r].w;
            }
#pragma unroll
            for (int dd = 0; dd < 4; ++dd) {
                u16x4 hv;
#pragma unroll
                for (int r = 0; r < 4; ++r) hv[r] = f2bf(a[r][dd]);
                *(u16x4*)&Vt[bufi][vd4 * 4 + dd][vky4 * 4] = hv;
            }
        }
    };

    auto computeTile = [&](int bufi, int stile) {
        // ---- QK^T: read swizzled K, convert to bf16, 8 MFMAs ----
        f32x4 sacc0 = {0.f, 0.f, 0.f, 0.f}, sacc1 = {0.f, 0.f, 0.f, 0.f};
#pragma unroll
        for (int kt = 0; kt < 2; ++kt) {
            const int row = kt * 16 + col;
            const int rx = row & 7;
#pragma unroll
            for (int ks = 0; ks < 4; ++ks) {
                const int sl = ks * 8 + g * 2;
                float4 a = *(const float4*)&Ksw[bufi][row][(sl ^ rx) * 4];
                float4 bb = *(const float4*)&Ksw[bufi][row][((sl + 1) ^ rx) * 4];
                float f[8] = {a.x, a.y, a.z, a.w, bb.x, bb.y, bb.z, bb.w};
                union { bf16x8 v; __hip_bfloat162 h2[4]; } W;
#pragma unroll
                for (int i = 0; i < 4; ++i)
                    W.h2[i] = __float22bfloat162_rn(make_float2(f[2 * i], f[2 * i + 1]));
                if (kt == 0)
                    sacc0 = __builtin_amdgcn_mfma_f32_16x16x32_bf16(qf[ks], W.v, sacc0, 0, 0, 0);
                else
                    sacc1 = __builtin_amdgcn_mfma_f32_16x16x32_bf16(qf[ks], W.v, sacc1, 0, 0, 0);
            }
        }

        // ---- mask + online softmax ----
        float rj[4];
        const int skey0 = stile + col, skey1 = stile + 16 + col;
#pragma unroll
        for (int j = 0; j < 4; ++j) {
            bool v0 = (skey0 < s1) && (skey0 - st <= qpos_r[j]) &&
                      (((skey0 >= st) ? 1 : 0) == segid_r[j]);
            bool v1 = (skey1 < s1) && (skey1 - st <= qpos_r[j]) &&
                      (((skey1 >= st) ? 1 : 0) == segid_r[j]);
            float lg0 = v0 ? sacc0[j] : NEG_INF;
            float lg1 = v1 ? sacc1[j] : NEG_INF;
            float tm = fmaxf(lg0, lg1);
            tm = fmaxf(tm, __shfl_xor(tm, 1));
            tm = fmaxf(tm, __shfl_xor(tm, 2));
            tm = fmaxf(tm, __shfl_xor(tm, 4));
            tm = fmaxf(tm, __shfl_xor(tm, 8));
            float mn = fmaxf(m[j], tm);
            float r, p0, p1;
            if (mn == NEG_INF) { r = 1.f; p0 = 0.f; p1 = 0.f; }
            else {
                r  = __expf(m[j] - mn);
                p0 = __expf(lg0 - mn);
                p1 = __expf(lg1 - mn);
            }
            float ps = p0 + p1;
            ps += __shfl_xor(ps, 1);
            ps += __shfl_xor(ps, 2);
            ps += __shfl_xor(ps, 4);
            ps += __shfl_xor(ps, 8);
            lsum[j] = lsum[j] * r + ps;
            m[j] = mn;
            rj[j] = r;
            int row = g * 4 + j;
            Pl[wave][row][col]      = f2bf(p0);
            Pl[wave][row][16 + col] = f2bf(p1);
        }

#pragma unroll
        for (int nt = 0; nt < 8; ++nt) {
#pragma unroll
            for (int j = 0; j < 4; ++j) oacc[nt][j] *= rj[j];
        }

        // ---- PV ----
        bf16x8 pa = *(const bf16x8*)&Pl[wave][col][g * 8];
#pragma unroll
        for (int nt = 0; nt < 8; ++nt) {
            bf16x8 vb = *(const bf16x8*)&Vt[bufi][nt * 16 + col][g * 8];
            oacc[nt] = __builtin_amdgcn_mfma_f32_16x16x32_bf16(pa, vb, oacc[nt], 0, 0, 0);
        }
    };

    // ---- prologue: stage tile 0 into buffer 0 ----
    const int ntiles = (s1 - s0 + 31) >> 5;
    float4 vA[4], vB[4];
    stageK(0, s0);
    loadV(vA, s0);
    writeV(0, vA);
    __syncthreads();

    // ---- 2-phase main loop (stage-next BEFORE compute-current) ----
    for (int ti = 0; ti < ntiles; ti += 2) {
        // phase 0: compute buf0 @ tile ti; stage buf1 @ tile ti+1
        if (ti + 1 < ntiles) { stageK(1, s0 + (ti + 1) * 32); loadV(vB, s0 + (ti + 1) * 32); }
        computeTile(0, s0 + ti * 32);
        if (ti + 1 < ntiles) writeV(1, vB);
        __syncthreads();
        // phase 1: compute buf1 @ tile ti+1; stage buf0 @ tile ti+2
        if (ti + 1 < ntiles) {
            if (ti + 2 < ntiles) { stageK(0, s0 + (ti + 2) * 32); loadV(vA, s0 + (ti + 2) * 32); }
            computeTile(1, s0 + (ti + 1) * 32);
            if (ti + 2 < ntiles) writeV(0, vA);
            __syncthreads();
        }
    }

    // ---- write partials ----
    const size_t base_q = (((size_t)chunk * B_ + b) * KH_ + kh) * 96;
#pragma unroll
    for (int j = 0; j < 4; ++j) {
        int qi = qbase + g * 4 + j;
        size_t pb = (base_q + qi) * 132;
        if (col == 0) { part[pb] = m[j]; part[pb + 1] = lsum[j]; }
#pragma unroll
        for (int nt = 0; nt < 8; ++nt)
            part[pb + 2 + nt * 16 + col] = oacc[nt][j];
    }
}

// ---------------------------------------------------------------------------
// Combine per-chunk partials -> qkv (b,t,N,H)
// ---------------------------------------------------------------------------
__global__ __launch_bounds__(256) void combine_kernel(
    const float* __restrict__ part, float* __restrict__ qkv)
{
    const int row = blockIdx.x;
    const int b = row >> 4, t = row & 15;
    const int tid = threadIdx.x;
    const int half = tid >> 7, h = tid & 127;
    const size_t cstride = (size_t)B_ * KH_ * 96 * 132;

    for (int nb = 0; nb < N_; nb += 2) {
        int n = nb + half;
        int kh = n / G_, g = n - kh * G_;
        int qi = t * G_ + g;
        size_t base0 = (((size_t)b * KH_ + kh) * 96 + qi) * 132;
        float M = -__builtin_inff();
        for (int c = 0; c < NCHUNK; ++c)
            M = fmaxf(M, part[base0 + c * cstride]);
        float den = 0.f, num = 0.f;
        for (int c = 0; c < NCHUNK; ++c) {
            float mc = part[base0 + c * cstride];
            float e = (M == -__builtin_inff() || mc == -__builtin_inff())
                          ? 0.f : expf(mc - M);
            den += e * part[base0 + c * cstride + 1];
            num += e * part[base0 + c * cstride + 2 + h];
        }
        qkv[(size_t)row * (N_ * H_) + n * H_ + h] = (den > 0.f) ? num / den : 0.f;
    }
}

// ---------------------------------------------------------------------------
__global__ __launch_bounds__(256) void sum_reduce(
    const float* __restrict__ part, float* __restrict__ out, int n)
{
    int i = blockIdx.x * 256 + threadIdx.x;
    if (i < n) {
        float s = 0.f;
#pragma unroll
        for (int sp = 0; sp < SPLITS; ++sp) s += part[(size_t)sp * n + i];
        out[i] = s;
    }
}

// ---------------------------------------------------------------------------
extern "C" void kernel_launch(void* const* d_in, const int* in_sizes, int n_in,
                              void* d_out, int out_size, void* d_ws, size_t ws_size,
                              hipStream_t stream)
{
    (void)in_sizes; (void)n_in; (void)out_size; (void)ws_size;
    const float* x       = (const float*)d_in[0];
    const float* k_cache = (const float*)d_in[1];
    const float* v_cache = (const float*)d_in[2];
    const float* wq      = (const float*)d_in[3];
    const float* bq      = (const float*)d_in[4];
    const float* wk      = (const float*)d_in[5];
    const float* bk      = (const float*)d_in[6];
    const float* wv      = (const float*)d_in[7];
    const float* bv      = (const float*)d_in[8];
    const float* wo      = (const float*)d_in[9];
    const int*   seg     = (const int*)d_in[10];
    const int*   start_i = (const int*)d_in[11];
    const int*   curp    = (const int*)d_in[12];
    float* out = (float*)d_out;
    float* ws  = (float*)d_ws;

    const size_t PSZ  = (size_t)NCHUNK * B_ * KH_ * 96 * 132; // 3,244,032
    const size_t QSZ  = (size_t)B_ * T_ * N_ * H_;            // 196,608
    const size_t KSZ  = (size_t)B_ * T_ * KH_ * H_;           // 32,768
    float* partP  = ws;
    float* partA  = ws;
    float* q_rope = ws + PSZ;
    float* k_new  = q_rope + QSZ;
    float* v_new  = k_new + KSZ;
    float* qkv    = v_new + KSZ;

    gemm_splitk<<<dim3(32, 2, SPLITS), 256, 0, stream>>>(
        x, wq, 1536, 1536, wk, 256, 256, wv, 256, partP, 2048, D_);

    rope_reduce<<<B_ * T_, 256, 0, stream>>>(partP, bq, bk, bv, seg, curp,
                                             q_rope, k_new, v_new);

    attn_mfma<<<dim3(NCHUNK, B_, KH_), 384, 0, stream>>>(
        q_rope, k_new, v_new, k_cache, v_cache, seg, start_i, curp, partA);

    combine_kernel<<<B_ * T_, 256, 0, stream>>>(partA, qkv);

    gemm_splitk<<<dim3(24, 2, SPLITS), 256, 0, stream>>>(
        qkv, wo, 1536, 1536, wo, 0, 1536, wo, 1536, partP, 1536, N_ * H_);

    sum_reduce<<<(B_ * T_ * D_ + 255) / 256, 256, 0, stream>>>(
        partP, out, B_ * T_ * D_);
}